// Round 1
// baseline (4748.483 us; speedup 1.0000x reference)
//
#include <hip/hip_runtime.h>
#include <math.h>

#define N_NODES 8192
#define N_EDGES 131072
#define C 32
#define Zn 10
#define NG 16
#define NSH 9
#define NB 8
#define H 64

__device__ __forceinline__ float silu_f(float v){ return v / (1.0f + __expf(-v)); }

// ---------------------------------------------------------------- geometry
__global__ __launch_bounds__(128)
void geom_kernel(const float* __restrict__ pos, const int* __restrict__ ei,
                 float* __restrict__ Yt, float* __restrict__ RBt){
  int e = blockIdx.x*128 + threadIdx.x;
  int snd = ei[e], rcv = ei[N_EDGES + e];
  float px = pos[rcv*3+0]-pos[snd*3+0];
  float py = pos[rcv*3+1]-pos[snd*3+1];
  float pz = pos[rcv*3+2]-pos[snd*3+2];
  float r2 = px*px+py*py+pz*pz + 1e-12f;
  float r = sqrtf(r2);
  float inv = 1.0f/r;
  float x = px*inv, y = py*inv, z = pz*inv;
  const float s3 = 1.7320508075688772f;
  const float s5 = 2.23606797749979f;
  const float s15 = 3.872983346207417f;
  Yt[0*N_EDGES+e] = 1.0f;
  Yt[1*N_EDGES+e] = s3*x;
  Yt[2*N_EDGES+e] = s3*y;
  Yt[3*N_EDGES+e] = s3*z;
  Yt[4*N_EDGES+e] = s15*x*y;
  Yt[5*N_EDGES+e] = s15*y*z;
  Yt[6*N_EDGES+e] = 0.5f*s5*(3.0f*z*z-1.0f);
  Yt[7*N_EDGES+e] = s15*x*z;
  Yt[8*N_EDGES+e] = 0.5f*s15*(x*x-y*y);
  float xr = r * 0.2f;                       // r / R_MAX
  float env = 0.0f;
  if (xr < 1.0f){
    float x2 = xr*xr;
    float x5 = x2*x2*xr;
    env = 1.0f - 21.0f*x5 + 35.0f*x5*xr - 15.0f*x5*x2;
  }
  const float pref = 0.6324555320336759f;    // sqrt(2/5)
  float sc = pref * inv * env;
  const float piOverR = 0.6283185307179586f; // pi/5
  #pragma unroll
  for (int n = 1; n <= NB; n++){
    RBt[(n-1)*N_EDGES+e] = sc * sinf((float)n * piOverR * r);
  }
}

// ---------------------------------------------------------------- init
__global__ __launch_bounds__(256)
void init_kernel(const float* __restrict__ na, const float* __restrict__ ae,
                 const float* __restrict__ Wemb, const float* __restrict__ charges,
                 const float* __restrict__ pos, const int* __restrict__ batch,
                 int* __restrict__ species, float* __restrict__ hg,
                 float* __restrict__ out){
  int idx = blockIdx.x*256 + threadIdx.x;       // [0, N*288)
  if (idx >= N_NODES*288) return;
  int n = idx / 288;
  int r = idx - n*288;
  int spec = 0;
  #pragma unroll
  for (int z = 1; z < Zn; z++) if (na[n*Zn+z] > 0.5f) spec = z;
  float hv = 0.0f;
  if (r < C) hv = Wemb[spec*C + r];
  hg[idx] = hv;
  if (r == 0){
    species[n] = spec;
    atomicAdd(out + batch[n]*4, ae[spec]);
  }
  if (r < 3){
    atomicAdd(out + batch[n]*4 + 1 + r, charges[n]*pos[n*3+r]);
  }
}

// ---------------------------------------------------------------- edge MLP + scatter
__global__ __launch_bounds__(128)
void edge_kernel(const float* __restrict__ R0i, const float* __restrict__ R1i,
                 const float* __restrict__ R2i, const float* __restrict__ R3i,
                 const float* __restrict__ Yt, const float* __restrict__ RBt,
                 const float* __restrict__ hg, const int* __restrict__ ei,
                 float* __restrict__ Ag){
  __shared__ float xsh[H*128];                 // per-thread activation column
  int tid = threadIdx.x;
  int e = blockIdx.x*128 + tid;

  #pragma unroll
  for (int k = 0; k < NB; k++) xsh[k*128+tid] = RBt[k*N_EDGES+e];

  float acc[H];
  // layer 0: 8 -> 64
  #pragma unroll
  for (int j = 0; j < H; j++) acc[j] = 0.f;
  for (int k = 0; k < NB; k++){
    float xk = xsh[k*128+tid];
    const float* w = R0i + k*H;                // wave-uniform -> s_load
    #pragma unroll
    for (int j = 0; j < H; j++) acc[j] = fmaf(xk, w[j], acc[j]);
  }
  #pragma unroll
  for (int j = 0; j < H; j++) xsh[j*128+tid] = silu_f(acc[j]);

  // layer 1: 64 -> 64
  #pragma unroll
  for (int j = 0; j < H; j++) acc[j] = 0.f;
  for (int k = 0; k < H; k++){
    float xk = xsh[k*128+tid];
    const float* w = R1i + k*H;
    #pragma unroll
    for (int j = 0; j < H; j++) acc[j] = fmaf(xk, w[j], acc[j]);
  }
  #pragma unroll
  for (int j = 0; j < H; j++) xsh[j*128+tid] = silu_f(acc[j]);

  // layer 2: 64 -> 64
  #pragma unroll
  for (int j = 0; j < H; j++) acc[j] = 0.f;
  for (int k = 0; k < H; k++){
    float xk = xsh[k*128+tid];
    const float* w = R2i + k*H;
    #pragma unroll
    for (int j = 0; j < H; j++) acc[j] = fmaf(xk, w[j], acc[j]);
  }
  #pragma unroll
  for (int j = 0; j < H; j++) xsh[j*128+tid] = silu_f(acc[j]);

  // layer 3: 64 -> 96 (3 chunks of 32) + message scatter
  int snd = ei[e], rcv = ei[N_EDGES+e];
  float hsv[C];
  #pragma unroll
  for (int c = 0; c < C; c++) hsv[c] = hg[snd*288 + c];
  float Yv[NSH];
  #pragma unroll
  for (int m = 0; m < NSH; m++) Yv[m] = Yt[m*N_EDGES+e];
  float* Arow = Ag + (long)rcv*288;

  #pragma unroll
  for (int l = 0; l < 3; l++){
    float a3[C];
    #pragma unroll
    for (int j = 0; j < C; j++) a3[j] = 0.f;
    for (int k = 0; k < H; k++){
      float xk = xsh[k*128+tid];
      const float* w = R3i + k*96 + l*32;
      #pragma unroll
      for (int j = 0; j < C; j++) a3[j] = fmaf(xk, w[j], a3[j]);
    }
    if (l == 0){
      #pragma unroll
      for (int c = 0; c < C; c++){
        atomicAdd(Arow + c, a3[c]*hsv[c]*Yv[0]);
      }
    } else if (l == 1){
      #pragma unroll
      for (int c = 0; c < C; c++){
        float t = a3[c]*hsv[c];
        atomicAdd(Arow + 32 + c, t*Yv[1]);
        atomicAdd(Arow + 64 + c, t*Yv[2]);
        atomicAdd(Arow + 96 + c, t*Yv[3]);
      }
    } else {
      #pragma unroll
      for (int c = 0; c < C; c++){
        float t = a3[c]*hsv[c];
        atomicAdd(Arow + 128 + c, t*Yv[4]);
        atomicAdd(Arow + 160 + c, t*Yv[5]);
        atomicAdd(Arow + 192 + c, t*Yv[6]);
        atomicAdd(Arow + 224 + c, t*Yv[7]);
        atomicAdd(Arow + 256 + c, t*Yv[8]);
      }
    }
  }
}

// ---------------------------------------------------------------- node update
__global__ __launch_bounds__(256)
void node_kernel(const float* __restrict__ Ag, float* __restrict__ hg,
                 const float* __restrict__ Wm_g, const float* __restrict__ Ws_g,
                 const float* __restrict__ Wp1, const float* __restrict__ Wp2,
                 const float* __restrict__ Wp3,
                 const int* __restrict__ species, const int* __restrict__ batch,
                 const float* __restrict__ wEv, const float* __restrict__ wDv,
                 const float* __restrict__ Whg, const float* __restrict__ wE2g,
                 int iter, float* __restrict__ out){
  __shared__ float Wm[3*32*32];
  __shared__ float Ws[3*32*32];
  __shared__ float abuf[4][288];
  __shared__ float hbuf[4][288];
  int tid = threadIdx.x;
  for (int t = tid; t < 3072; t += 256){ Wm[t] = Wm_g[t]; Ws[t] = Ws_g[t]; }
  int w = tid >> 6, lane = tid & 63;
  int n = blockIdx.x*4 + w;
  for (int idx = lane; idx < 288; idx += 64){
    abuf[w][idx] = Ag[(long)n*288+idx] * (1.0f/16.0f);
    hbuf[w][idx] = hg[(long)n*288+idx];
  }
  __syncthreads();

  float amv[5], scv[5];
  #pragma unroll
  for (int it = 0; it < 5; it++){
    int idx = it*64 + lane;
    amv[it] = 0.f; scv[it] = 0.f;
    if (idx < 288){
      int m = idx >> 5, d = idx & 31;
      int l = (m >= 4) ? 2 : ((m >= 1) ? 1 : 0);
      const float* wm = Wm + l*1024 + d;
      const float* ws = Ws + l*1024 + d;
      float a2 = 0.f, sc = 0.f;
      #pragma unroll
      for (int c = 0; c < 32; c++){
        a2 = fmaf(abuf[w][m*32+c], wm[c*32], a2);
        sc = fmaf(hbuf[w][m*32+c], ws[c*32], sc);
      }
      amv[it] = a2; scv[it] = sc;
    }
  }
  __syncthreads();
  #pragma unroll
  for (int it = 0; it < 5; it++){ int idx = it*64+lane; if (idx < 288) abuf[w][idx] = amv[it]; }
  __syncthreads();

  int d = lane & 31;
  float sval = abuf[w][d];
  int spec = species[n];
  float p1 = Wp1[spec*C+d], p2 = Wp2[spec*C+d], p3 = Wp3[spec*C+d];
  float f = p1 + p2*sval + p3*sval*sval;
  #pragma unroll
  for (int it = 0; it < 5; it++){
    int idx = it*64 + lane;
    if (idx < 288){
      float hn = amv[it]*f + scv[it];
      hg[(long)n*288+idx] = hn;
      hbuf[w][idx] = hn;
    }
  }
  __syncthreads();

  int g = batch[n];
  float dv0 = 0.f, dv1 = 0.f, dv2 = 0.f, ev = 0.f;
  if (lane < 32){
    dv0 = hbuf[w][32+lane]*wDv[lane];
    dv1 = hbuf[w][64+lane]*wDv[lane];
    dv2 = hbuf[w][96+lane]*wDv[lane];
  }
  if (iter == 0){
    if (lane < 32) ev = hbuf[w][lane]*wEv[lane];
  } else {
    if (lane < 16){
      float hid = 0.f;
      #pragma unroll
      for (int c = 0; c < 32; c++) hid = fmaf(hbuf[w][c], Whg[c*16+lane], hid);
      hid = silu_f(hid);
      ev = hid * wE2g[lane];
    }
  }
  #pragma unroll
  for (int off = 16; off >= 1; off >>= 1){
    ev  += __shfl_down(ev,  off);
    dv0 += __shfl_down(dv0, off);
    dv1 += __shfl_down(dv1, off);
    dv2 += __shfl_down(dv2, off);
  }
  if (lane == 0){
    atomicAdd(out + g*4 + 0, ev);
    atomicAdd(out + g*4 + 1, dv0);
    atomicAdd(out + g*4 + 2, dv1);
    atomicAdd(out + g*4 + 3, dv2);
  }
}

// ---------------------------------------------------------------- launch
extern "C" void kernel_launch(void* const* d_in, const int* in_sizes, int n_in,
                              void* d_out, int out_size, void* d_ws, size_t ws_size,
                              hipStream_t stream){
  const float* positions       = (const float*)d_in[0];
  const float* node_attrs      = (const float*)d_in[1];
  const float* charges         = (const float*)d_in[2];
  const float* atomic_energies = (const float*)d_in[3];
  const float* W_embed         = (const float*)d_in[4];
  const float* R0              = (const float*)d_in[5];
  const float* R1              = (const float*)d_in[6];
  const float* R2              = (const float*)d_in[7];
  const float* R3              = (const float*)d_in[8];
  const float* W_mix           = (const float*)d_in[9];
  const float* W_sc            = (const float*)d_in[10];
  const float* Wp1             = (const float*)d_in[11];
  const float* Wp2             = (const float*)d_in[12];
  const float* Wp3             = (const float*)d_in[13];
  const float* wE1             = (const float*)d_in[14];
  const float* wD1             = (const float*)d_in[15];
  const float* Wh              = (const float*)d_in[16];
  const float* wE2             = (const float*)d_in[17];
  const float* wD2             = (const float*)d_in[18];
  const int*   edge_index      = (const int*)d_in[19];
  const int*   batch           = (const int*)d_in[20];
  float* out = (float*)d_out;

  char* wsp = (char*)d_ws;
  float* Yt  = (float*)wsp; wsp += sizeof(float)*(size_t)NSH*N_EDGES;
  float* RBt = (float*)wsp; wsp += sizeof(float)*(size_t)NB*N_EDGES;
  float* hg  = (float*)wsp; wsp += sizeof(float)*(size_t)N_NODES*288;
  float* Ag  = (float*)wsp; wsp += sizeof(float)*(size_t)N_NODES*288;
  int* species = (int*)wsp; wsp += sizeof(int)*N_NODES;

  hipMemsetAsync(d_out, 0, 64*sizeof(float), stream);
  init_kernel<<<9216, 256, 0, stream>>>(node_attrs, atomic_energies, W_embed,
                                        charges, positions, batch, species, hg, out);
  geom_kernel<<<N_EDGES/128, 128, 0, stream>>>(positions, edge_index, Yt, RBt);

  for (int i = 0; i < 2; i++){
    hipMemsetAsync(Ag, 0, sizeof(float)*(size_t)N_NODES*288, stream);
    edge_kernel<<<N_EDGES/128, 128, 0, stream>>>(R0 + i*NB*H, R1 + i*H*H, R2 + i*H*H,
                                                 R3 + i*H*96, Yt, RBt, hg, edge_index, Ag);
    node_kernel<<<N_NODES/4, 256, 0, stream>>>(Ag, hg, W_mix + i*3*C*C, W_sc + i*3*C*C,
                                               Wp1 + i*Zn*C, Wp2 + i*Zn*C, Wp3 + i*Zn*C,
                                               species, batch,
                                               wE1, (i == 0) ? wD1 : wD2,
                                               Wh, wE2, i, out);
  }
}

// Round 2
// 1169.823 us; speedup vs baseline: 4.0591x; 4.0591x over previous
//
#include <hip/hip_runtime.h>
#include <math.h>

#define N_NODES 8192
#define N_EDGES 131072
#define C 32
#define Zn 10
#define NG 16
#define NSH 9
#define NB 8
#define H 64

__device__ __forceinline__ float silu_f(float v){ return v / (1.0f + __expf(-v)); }

// ---------------------------------------------------------------- geometry
// writes RBt edge-major [k][E] (for coalesced edge-kernel reads) and
// Ye per-edge [e][16] (padded, for gather-side reads)
__global__ __launch_bounds__(128)
void geom_kernel(const float* __restrict__ pos, const int* __restrict__ ei,
                 float* __restrict__ Ye, float* __restrict__ RBt){
  int e = blockIdx.x*128 + threadIdx.x;
  int snd = ei[e], rcv = ei[N_EDGES + e];
  float px = pos[rcv*3+0]-pos[snd*3+0];
  float py = pos[rcv*3+1]-pos[snd*3+1];
  float pz = pos[rcv*3+2]-pos[snd*3+2];
  float r2 = px*px+py*py+pz*pz + 1e-12f;
  float r = sqrtf(r2);
  float inv = 1.0f/r;
  float x = px*inv, y = py*inv, z = pz*inv;
  const float s3 = 1.7320508075688772f;
  const float s5 = 2.23606797749979f;
  const float s15 = 3.872983346207417f;
  float* ye = Ye + (size_t)e*16;
  ye[0] = 1.0f;
  ye[1] = s3*x;
  ye[2] = s3*y;
  ye[3] = s3*z;
  ye[4] = s15*x*y;
  ye[5] = s15*y*z;
  ye[6] = 0.5f*s5*(3.0f*z*z-1.0f);
  ye[7] = s15*x*z;
  ye[8] = 0.5f*s15*(x*x-y*y);
  float xr = r * 0.2f;                       // r / R_MAX
  float env = 0.0f;
  if (xr < 1.0f){
    float x2 = xr*xr;
    float x5 = x2*x2*xr;
    env = 1.0f - 21.0f*x5 + 35.0f*x5*xr - 15.0f*x5*x2;
  }
  const float pref = 0.6324555320336759f;    // sqrt(2/5)
  float sc = pref * inv * env;
  const float piOverR = 0.6283185307179586f; // pi/5
  #pragma unroll
  for (int n = 1; n <= NB; n++){
    RBt[(n-1)*N_EDGES+e] = sc * sinf((float)n * piOverR * r);
  }
}

// ---------------------------------------------------------------- init
__global__ __launch_bounds__(256)
void init_kernel(const float* __restrict__ na, const float* __restrict__ ae,
                 const float* __restrict__ Wemb, const float* __restrict__ charges,
                 const float* __restrict__ pos, const int* __restrict__ batch,
                 int* __restrict__ species, float* __restrict__ hg,
                 float* __restrict__ out){
  int idx = blockIdx.x*256 + threadIdx.x;       // [0, N*288)
  if (idx >= N_NODES*288) return;
  int n = idx / 288;
  int r = idx - n*288;
  int spec = 0;
  #pragma unroll
  for (int z = 1; z < Zn; z++) if (na[n*Zn+z] > 0.5f) spec = z;
  float hv = 0.0f;
  if (r < C) hv = Wemb[spec*C + r];
  hg[idx] = hv;
  if (r == 0){
    species[n] = spec;
    atomicAdd(out + batch[n]*4, ae[spec]);
  }
  if (r < 3){
    atomicAdd(out + batch[n]*4 + 1 + r, charges[n]*pos[n*3+r]);
  }
}

// ---------------------------------------------------------------- CSR build
__global__ __launch_bounds__(256)
void hist_kernel(const int* __restrict__ ei, int* __restrict__ counts){
  int e = blockIdx.x*256 + threadIdx.x;
  atomicAdd(counts + ei[N_EDGES + e], 1);
}

__global__ __launch_bounds__(256)
void scan_kernel(const int* __restrict__ counts, int* __restrict__ row_start,
                 int* __restrict__ cursor){
  __shared__ int part[256];
  int tid = threadIdx.x;
  int base = tid*32;
  int local[32];
  int s = 0;
  #pragma unroll
  for (int i = 0; i < 32; i++){ local[i] = s; s += counts[base+i]; }
  part[tid] = s; __syncthreads();
  for (int off = 1; off < 256; off <<= 1){
    int v = (tid >= off) ? part[tid-off] : 0;
    __syncthreads();
    part[tid] += v;
    __syncthreads();
  }
  int excl = part[tid] - s;
  #pragma unroll
  for (int i = 0; i < 32; i++){
    int v = excl + local[i];
    row_start[base+i] = v;
    cursor[base+i] = v;
  }
  if (tid == 255) row_start[N_NODES] = part[255];
}

__global__ __launch_bounds__(256)
void fill_kernel(const int* __restrict__ ei, int* __restrict__ cursor,
                 int* __restrict__ order){
  int e = blockIdx.x*256 + threadIdx.x;
  int rcv = ei[N_EDGES + e];
  int pos = atomicAdd(cursor + rcv, 1);
  order[pos] = e;
}

// ---------------------------------------------------------------- edge MLP
// writes P[e][96] = (x @ R3) * h_snd  (Y applied at gather time; no atomics)
__global__ __launch_bounds__(128)
void edge_kernel(const float* __restrict__ R0i, const float* __restrict__ R1i,
                 const float* __restrict__ R2i, const float* __restrict__ R3i,
                 const float* __restrict__ RBt,
                 const float* __restrict__ hg, const int* __restrict__ ei,
                 float* __restrict__ P){
  __shared__ float xsh[H*128];                 // per-thread activation column
  __shared__ float tile[128*36];               // staging for coalesced P writes
  int tid = threadIdx.x;
  int e = blockIdx.x*128 + tid;

  #pragma unroll
  for (int k = 0; k < NB; k++) xsh[k*128+tid] = RBt[k*N_EDGES+e];

  float acc[H];
  // layer 0: 8 -> 64
  #pragma unroll
  for (int j = 0; j < H; j++) acc[j] = 0.f;
  for (int k = 0; k < NB; k++){
    float xk = xsh[k*128+tid];
    const float* w = R0i + k*H;                // wave-uniform -> s_load
    #pragma unroll
    for (int j = 0; j < H; j++) acc[j] = fmaf(xk, w[j], acc[j]);
  }
  #pragma unroll
  for (int j = 0; j < H; j++) xsh[j*128+tid] = silu_f(acc[j]);

  // layer 1: 64 -> 64
  #pragma unroll
  for (int j = 0; j < H; j++) acc[j] = 0.f;
  for (int k = 0; k < H; k++){
    float xk = xsh[k*128+tid];
    const float* w = R1i + k*H;
    #pragma unroll
    for (int j = 0; j < H; j++) acc[j] = fmaf(xk, w[j], acc[j]);
  }
  #pragma unroll
  for (int j = 0; j < H; j++) xsh[j*128+tid] = silu_f(acc[j]);

  // layer 2: 64 -> 64
  #pragma unroll
  for (int j = 0; j < H; j++) acc[j] = 0.f;
  for (int k = 0; k < H; k++){
    float xk = xsh[k*128+tid];
    const float* w = R2i + k*H;
    #pragma unroll
    for (int j = 0; j < H; j++) acc[j] = fmaf(xk, w[j], acc[j]);
  }
  #pragma unroll
  for (int j = 0; j < H; j++) xsh[j*128+tid] = silu_f(acc[j]);

  // layer 3: 64 -> 96 (3 chunks of 32), premultiplied by h_snd, staged + coalesced out
  int snd = ei[e];
  float hsv[C];
  #pragma unroll
  for (int c = 0; c < C; c++) hsv[c] = hg[snd*288 + c];

  const size_t pbase = (size_t)blockIdx.x*128*96;

  #pragma unroll
  for (int l = 0; l < 3; l++){
    float a3[C];
    #pragma unroll
    for (int j = 0; j < C; j++) a3[j] = 0.f;
    for (int k = 0; k < H; k++){
      float xk = xsh[k*128+tid];
      const float* w = R3i + k*96 + l*32;
      #pragma unroll
      for (int j = 0; j < C; j++) a3[j] = fmaf(xk, w[j], a3[j]);
    }
    #pragma unroll
    for (int c = 0; c < C; c++) tile[tid*36 + c] = a3[c]*hsv[c];
    __syncthreads();
    #pragma unroll
    for (int it = 0; it < 8; it++){
      int linear = it*128 + tid;               // 0..1023
      int el = linear >> 3, c4 = linear & 7;
      float4 v = *(const float4*)(tile + el*36 + (c4<<2));
      *(float4*)(P + pbase + (size_t)el*96 + (l<<5) + (c4<<2)) = v;
    }
    __syncthreads();
  }
}

// ---------------------------------------------------------------- node: gather + mix + gate + readout
__global__ __launch_bounds__(256)
void node_kernel(const float* __restrict__ P, const float* __restrict__ Ye,
                 const int* __restrict__ order, const int* __restrict__ row_start,
                 float* __restrict__ hg,
                 const float* __restrict__ Wm_g, const float* __restrict__ Ws_g,
                 const float* __restrict__ Wp1, const float* __restrict__ Wp2,
                 const float* __restrict__ Wp3,
                 const int* __restrict__ species, const int* __restrict__ batch,
                 const float* __restrict__ wEv, const float* __restrict__ wDv,
                 const float* __restrict__ Whg, const float* __restrict__ wE2g,
                 int iter, float* __restrict__ out){
  __shared__ float Wm[3*32*32];
  __shared__ float Ws[3*32*32];
  __shared__ float abuf[4][288];
  __shared__ float hbuf[4][288];
  int tid = threadIdx.x;
  for (int t = tid; t < 3072; t += 256){ Wm[t] = Wm_g[t]; Ws[t] = Ws_g[t]; }
  int w = tid >> 6, lane = tid & 63;
  int n = blockIdx.x*4 + w;
  for (int idx = lane; idx < 288; idx += 64){
    hbuf[w][idx] = hg[(long)n*288+idx];
  }

  // ---- gather A = sum_{e -> n} P[e][lmap[m]*32+c] * Ye[e][m]
  int cols[5], ms[5]; bool act[5];
  #pragma unroll
  for (int s = 0; s < 5; s++){
    int idx = lane + s*64;
    act[s] = (idx < 288);
    int m = act[s] ? (idx >> 5) : 0;
    int l = (m >= 4) ? 2 : ((m >= 1) ? 1 : 0);
    cols[s] = l*32 + (idx & 31);
    ms[s] = m;
  }
  float acc[5] = {0.f,0.f,0.f,0.f,0.f};
  int jb = row_start[n], je = row_start[n+1];
  #pragma unroll 2
  for (int j = jb; j < je; j++){
    int e = order[j];
    const float* Pe = P + (size_t)e*96;
    const float* Yv = Ye + (size_t)e*16;
    #pragma unroll
    for (int s = 0; s < 5; s++){
      if (act[s]) acc[s] = fmaf(Pe[cols[s]], Yv[ms[s]], acc[s]);
    }
  }
  #pragma unroll
  for (int s = 0; s < 5; s++){
    int idx = lane + s*64;
    if (act[s]) abuf[w][idx] = acc[s] * (1.0f/16.0f);
  }
  __syncthreads();

  // ---- mix: A @ W_mix[lmap], sc = h @ W_sc[lmap]
  float amv[5], scv[5];
  #pragma unroll
  for (int it = 0; it < 5; it++){
    int idx = it*64 + lane;
    amv[it] = 0.f; scv[it] = 0.f;
    if (idx < 288){
      int m = idx >> 5, d = idx & 31;
      int l = (m >= 4) ? 2 : ((m >= 1) ? 1 : 0);
      const float* wm = Wm + l*1024 + d;
      const float* ws = Ws + l*1024 + d;
      float a2 = 0.f, sc = 0.f;
      #pragma unroll
      for (int c = 0; c < 32; c++){
        a2 = fmaf(abuf[w][m*32+c], wm[c*32], a2);
        sc = fmaf(hbuf[w][m*32+c], ws[c*32], sc);
      }
      amv[it] = a2; scv[it] = sc;
    }
  }
  __syncthreads();
  #pragma unroll
  for (int it = 0; it < 5; it++){ int idx = it*64+lane; if (idx < 288) abuf[w][idx] = amv[it]; }
  __syncthreads();

  int d = lane & 31;
  float sval = abuf[w][d];
  int spec = species[n];
  float p1 = Wp1[spec*C+d], p2 = Wp2[spec*C+d], p3 = Wp3[spec*C+d];
  float f = p1 + p2*sval + p3*sval*sval;
  #pragma unroll
  for (int it = 0; it < 5; it++){
    int idx = it*64 + lane;
    if (idx < 288){
      float hn = amv[it]*f + scv[it];
      hg[(long)n*288+idx] = hn;
      hbuf[w][idx] = hn;
    }
  }
  __syncthreads();

  int g = batch[n];
  float dv0 = 0.f, dv1 = 0.f, dv2 = 0.f, ev = 0.f;
  if (lane < 32){
    dv0 = hbuf[w][32+lane]*wDv[lane];
    dv1 = hbuf[w][64+lane]*wDv[lane];
    dv2 = hbuf[w][96+lane]*wDv[lane];
  }
  if (iter == 0){
    if (lane < 32) ev = hbuf[w][lane]*wEv[lane];
  } else {
    if (lane < 16){
      float hid = 0.f;
      #pragma unroll
      for (int c = 0; c < 32; c++) hid = fmaf(hbuf[w][c], Whg[c*16+lane], hid);
      hid = silu_f(hid);
      ev = hid * wE2g[lane];
    }
  }
  #pragma unroll
  for (int off = 16; off >= 1; off >>= 1){
    ev  += __shfl_down(ev,  off);
    dv0 += __shfl_down(dv0, off);
    dv1 += __shfl_down(dv1, off);
    dv2 += __shfl_down(dv2, off);
  }
  if (lane == 0){
    atomicAdd(out + g*4 + 0, ev);
    atomicAdd(out + g*4 + 1, dv0);
    atomicAdd(out + g*4 + 2, dv1);
    atomicAdd(out + g*4 + 3, dv2);
  }
}

// ---------------------------------------------------------------- launch
extern "C" void kernel_launch(void* const* d_in, const int* in_sizes, int n_in,
                              void* d_out, int out_size, void* d_ws, size_t ws_size,
                              hipStream_t stream){
  const float* positions       = (const float*)d_in[0];
  const float* node_attrs      = (const float*)d_in[1];
  const float* charges         = (const float*)d_in[2];
  const float* atomic_energies = (const float*)d_in[3];
  const float* W_embed         = (const float*)d_in[4];
  const float* R0              = (const float*)d_in[5];
  const float* R1              = (const float*)d_in[6];
  const float* R2              = (const float*)d_in[7];
  const float* R3              = (const float*)d_in[8];
  const float* W_mix           = (const float*)d_in[9];
  const float* W_sc            = (const float*)d_in[10];
  const float* Wp1             = (const float*)d_in[11];
  const float* Wp2             = (const float*)d_in[12];
  const float* Wp3             = (const float*)d_in[13];
  const float* wE1             = (const float*)d_in[14];
  const float* wD1             = (const float*)d_in[15];
  const float* Wh              = (const float*)d_in[16];
  const float* wE2             = (const float*)d_in[17];
  const float* wD2             = (const float*)d_in[18];
  const int*   edge_index      = (const int*)d_in[19];
  const int*   batch           = (const int*)d_in[20];
  float* out = (float*)d_out;

  char* wsp = (char*)d_ws;
  float* P   = (float*)wsp; wsp += sizeof(float)*(size_t)N_EDGES*96;
  float* Ye  = (float*)wsp; wsp += sizeof(float)*(size_t)N_EDGES*16;
  float* RBt = (float*)wsp; wsp += sizeof(float)*(size_t)NB*N_EDGES;
  float* hg  = (float*)wsp; wsp += sizeof(float)*(size_t)N_NODES*288;
  int* counts    = (int*)wsp; wsp += sizeof(int)*N_NODES;
  int* row_start = (int*)wsp; wsp += sizeof(int)*(N_NODES+64);
  int* cursor    = (int*)wsp; wsp += sizeof(int)*N_NODES;
  int* order     = (int*)wsp; wsp += sizeof(int)*N_EDGES;
  int* species   = (int*)wsp; wsp += sizeof(int)*N_NODES;

  hipMemsetAsync(d_out, 0, 64*sizeof(float), stream);
  hipMemsetAsync(counts, 0, N_NODES*sizeof(int), stream);
  init_kernel<<<9216, 256, 0, stream>>>(node_attrs, atomic_energies, W_embed,
                                        charges, positions, batch, species, hg, out);
  geom_kernel<<<N_EDGES/128, 128, 0, stream>>>(positions, edge_index, Ye, RBt);
  hist_kernel<<<N_EDGES/256, 256, 0, stream>>>(edge_index, counts);
  scan_kernel<<<1, 256, 0, stream>>>(counts, row_start, cursor);
  fill_kernel<<<N_EDGES/256, 256, 0, stream>>>(edge_index, cursor, order);

  for (int i = 0; i < 2; i++){
    edge_kernel<<<N_EDGES/128, 128, 0, stream>>>(R0 + i*NB*H, R1 + i*H*H, R2 + i*H*H,
                                                 R3 + i*H*96, RBt, hg, edge_index, P);
    node_kernel<<<N_NODES/4, 256, 0, stream>>>(P, Ye, order, row_start, hg,
                                               W_mix + i*3*C*C, W_sc + i*3*C*C,
                                               Wp1 + i*Zn*C, Wp2 + i*Zn*C, Wp3 + i*Zn*C,
                                               species, batch,
                                               wE1, (i == 0) ? wD1 : wD2,
                                               Wh, wE2, i, out);
  }
}

// Round 3
// 443.342 us; speedup vs baseline: 10.7107x; 2.6386x over previous
//
#include <hip/hip_runtime.h>
#include <math.h>

#define N_NODES 8192
#define N_EDGES 131072
#define C 32
#define Zn 10
#define NG 16
#define NSH 9
#define NB 8
#define H 64

__device__ __forceinline__ float silu_f(float v){ return v / (1.0f + __expf(-v)); }

// ---------------------------------------------------------------- CSR build
__global__ __launch_bounds__(256)
void hist_kernel(const int* __restrict__ ei, int* __restrict__ counts){
  int e = blockIdx.x*256 + threadIdx.x;
  atomicAdd(counts + ei[N_EDGES + e], 1);
}

__global__ __launch_bounds__(256)
void scan_kernel(const int* __restrict__ counts, int* __restrict__ row_start,
                 int* __restrict__ cursor){
  __shared__ int part[256];
  int tid = threadIdx.x;
  int base = tid*32;
  int local[32];
  int s = 0;
  #pragma unroll
  for (int i = 0; i < 32; i++){ local[i] = s; s += counts[base+i]; }
  part[tid] = s; __syncthreads();
  for (int off = 1; off < 256; off <<= 1){
    int v = (tid >= off) ? part[tid-off] : 0;
    __syncthreads();
    part[tid] += v;
    __syncthreads();
  }
  int excl = part[tid] - s;
  #pragma unroll
  for (int i = 0; i < 32; i++){
    int v = excl + local[i];
    row_start[base+i] = v;
    cursor[base+i] = v;
  }
  if (tid == 255) row_start[N_NODES] = part[255];
}

__global__ __launch_bounds__(256)
void fill_kernel(const int* __restrict__ ei, int* __restrict__ cursor,
                 int* __restrict__ order){
  int e = blockIdx.x*256 + threadIdx.x;
  int rcv = ei[N_EDGES + e];
  int pos = atomicAdd(cursor + rcv, 1);
  order[pos] = e;
}

// ---------------------------------------------------------------- species + baseline outputs
__global__ __launch_bounds__(256)
void spec_kernel(const float* __restrict__ na, const float* __restrict__ ae,
                 const float* __restrict__ charges, const float* __restrict__ pos,
                 const int* __restrict__ batch, int* __restrict__ species,
                 float* __restrict__ out){
  __shared__ float glds[NG][4];
  int tid = threadIdx.x;
  if (tid < NG*4) glds[tid>>2][tid&3] = 0.f;
  __syncthreads();
  int n = blockIdx.x*256 + tid;
  int spec = 0;
  #pragma unroll
  for (int z = 1; z < Zn; z++) if (na[n*Zn+z] > 0.5f) spec = z;
  species[n] = spec;
  int g = batch[n];
  float q = charges[n];
  atomicAdd(&glds[g][0], ae[spec]);
  atomicAdd(&glds[g][1], q*pos[n*3+0]);
  atomicAdd(&glds[g][2], q*pos[n*3+1]);
  atomicAdd(&glds[g][3], q*pos[n*3+2]);
  __syncthreads();
  if (tid < NG*4){
    float v = glds[tid>>2][tid&3];
    if (v != 0.f) atomicAdd(out + tid, v);
  }
}

__global__ __launch_bounds__(256)
void h0_kernel(const int* __restrict__ species, const float* __restrict__ Wemb,
               float* __restrict__ hg){
  int idx = blockIdx.x*256 + threadIdx.x;        // [0, N*32)
  int n = idx >> 5, c = idx & 31;
  hg[(size_t)n*288 + c] = Wemb[species[n]*C + c];
}

// ---------------------------------------------------------------- geometry (CSR-slot order)
__global__ __launch_bounds__(128)
void geom_kernel(const float* __restrict__ pos, const int* __restrict__ ei,
                 const int* __restrict__ order, int* __restrict__ snd_perm,
                 float* __restrict__ Ye, float* __restrict__ RBt){
  int t = blockIdx.x*128 + threadIdx.x;          // CSR slot
  int e = order[t];
  int snd = ei[e], rcv = ei[N_EDGES + e];
  snd_perm[t] = snd;
  float px = pos[rcv*3+0]-pos[snd*3+0];
  float py = pos[rcv*3+1]-pos[snd*3+1];
  float pz = pos[rcv*3+2]-pos[snd*3+2];
  float r2 = px*px+py*py+pz*pz + 1e-12f;
  float r = sqrtf(r2);
  float inv = 1.0f/r;
  float x = px*inv, y = py*inv, z = pz*inv;
  const float s3 = 1.7320508075688772f;
  const float s5 = 2.23606797749979f;
  const float s15 = 3.872983346207417f;
  float* ye = Ye + (size_t)t*16;
  ye[0] = 1.0f;
  ye[1] = s3*x;
  ye[2] = s3*y;
  ye[3] = s3*z;
  ye[4] = s15*x*y;
  ye[5] = s15*y*z;
  ye[6] = 0.5f*s5*(3.0f*z*z-1.0f);
  ye[7] = s15*x*z;
  ye[8] = 0.5f*s15*(x*x-y*y);
  float xr = r * 0.2f;                       // r / R_MAX
  float env = 0.0f;
  if (xr < 1.0f){
    float x2 = xr*xr;
    float x5 = x2*x2*xr;
    env = 1.0f - 21.0f*x5 + 35.0f*x5*xr - 15.0f*x5*x2;
  }
  const float pref = 0.6324555320336759f;    // sqrt(2/5)
  float sc = pref * inv * env;
  const float piOverR = 0.6283185307179586f; // pi/5
  #pragma unroll
  for (int n = 1; n <= NB; n++){
    RBt[(n-1)*N_EDGES+t] = sc * sinf((float)n * piOverR * r);
  }
}

// ---------------------------------------------------------------- edge MLP (CSR-slot order)
// writes P[t][96] = (x @ R3) * h_snd  — contiguous rows, Y applied at gather
__global__ __launch_bounds__(128)
void edge_kernel(const float* __restrict__ R0i, const float* __restrict__ R1i,
                 const float* __restrict__ R2i, const float* __restrict__ R3i,
                 const float* __restrict__ RBt,
                 const float* __restrict__ hg, const int* __restrict__ snd_perm,
                 float* __restrict__ P){
  __shared__ float xsh[H*128];                 // per-thread activation column
  int tid = threadIdx.x;
  int t = blockIdx.x*128 + tid;

  #pragma unroll
  for (int k = 0; k < NB; k++) xsh[k*128+tid] = RBt[k*N_EDGES+t];

  float acc[H];
  // layer 0: 8 -> 64
  #pragma unroll
  for (int j = 0; j < H; j++) acc[j] = 0.f;
  for (int k = 0; k < NB; k++){
    float xk = xsh[k*128+tid];
    const float* w = R0i + k*H;                // wave-uniform -> s_load
    #pragma unroll
    for (int j = 0; j < H; j++) acc[j] = fmaf(xk, w[j], acc[j]);
  }
  #pragma unroll
  for (int j = 0; j < H; j++) xsh[j*128+tid] = silu_f(acc[j]);

  // layer 1: 64 -> 64
  #pragma unroll
  for (int j = 0; j < H; j++) acc[j] = 0.f;
  for (int k = 0; k < H; k++){
    float xk = xsh[k*128+tid];
    const float* w = R1i + k*H;
    #pragma unroll
    for (int j = 0; j < H; j++) acc[j] = fmaf(xk, w[j], acc[j]);
  }
  #pragma unroll
  for (int j = 0; j < H; j++) xsh[j*128+tid] = silu_f(acc[j]);

  // layer 2: 64 -> 64
  #pragma unroll
  for (int j = 0; j < H; j++) acc[j] = 0.f;
  for (int k = 0; k < H; k++){
    float xk = xsh[k*128+tid];
    const float* w = R2i + k*H;
    #pragma unroll
    for (int j = 0; j < H; j++) acc[j] = fmaf(xk, w[j], acc[j]);
  }
  #pragma unroll
  for (int j = 0; j < H; j++) xsh[j*128+tid] = silu_f(acc[j]);

  // layer 3: 64 -> 96 (3 chunks of 32), premultiplied by h_snd, direct row write
  int snd = snd_perm[t];
  float hsv[C];
  #pragma unroll
  for (int c = 0; c < C; c++) hsv[c] = hg[(size_t)snd*288 + c];

  float* Prow = P + (size_t)t*96;
  #pragma unroll
  for (int l = 0; l < 3; l++){
    float a3[C];
    #pragma unroll
    for (int j = 0; j < C; j++) a3[j] = 0.f;
    for (int k = 0; k < H; k++){
      float xk = xsh[k*128+tid];
      const float* w = R3i + k*96 + l*32;
      #pragma unroll
      for (int j = 0; j < C; j++) a3[j] = fmaf(xk, w[j], a3[j]);
    }
    #pragma unroll
    for (int c = 0; c < C; c += 4){
      float4 v = make_float4(a3[c]*hsv[c], a3[c+1]*hsv[c+1],
                             a3[c+2]*hsv[c+2], a3[c+3]*hsv[c+3]);
      *(float4*)(Prow + l*32 + c) = v;
    }
  }
}

// ---------------------------------------------------------------- node: contiguous gather + mix + gate + readout
__global__ __launch_bounds__(256)
void node_kernel(const float* __restrict__ P, const float* __restrict__ Ye,
                 const int* __restrict__ row_start,
                 float* __restrict__ hg,
                 const float* __restrict__ Wm_g, const float* __restrict__ Ws_g,
                 const float* __restrict__ Wp1, const float* __restrict__ Wp2,
                 const float* __restrict__ Wp3,
                 const int* __restrict__ species, const int* __restrict__ batch,
                 const float* __restrict__ wEv, const float* __restrict__ wDv,
                 const float* __restrict__ Whg, const float* __restrict__ wE2g,
                 int iter, float* __restrict__ out){
  __shared__ float Wm[3*32*32];
  __shared__ float Ws[3*32*32];
  __shared__ float abuf[4][288];
  __shared__ float hbuf[4][288];
  __shared__ float glds[NG][4];
  int tid = threadIdx.x;
  for (int t = tid; t < 3072; t += 256){ Wm[t] = Wm_g[t]; Ws[t] = Ws_g[t]; }
  if (tid < NG*4) glds[tid>>2][tid&3] = 0.f;
  int w = tid >> 6, lane = tid & 63;
  int n = blockIdx.x*4 + w;
  for (int idx = lane; idx < 288; idx += 64){
    hbuf[w][idx] = hg[(long)n*288+idx];
  }

  // ---- gather A[m][c] = sum_{slots j of n} P[j][lmap[m]*32+c] * Ye[j][m]
  int cols[5], ms[5]; bool act[5];
  #pragma unroll
  for (int s = 0; s < 5; s++){
    int idx = lane + s*64;
    act[s] = (idx < 288);
    int m = act[s] ? (idx >> 5) : 0;
    int l = (m >= 4) ? 2 : ((m >= 1) ? 1 : 0);
    cols[s] = l*32 + (idx & 31);
    ms[s] = m;
  }
  float acc[5] = {0.f,0.f,0.f,0.f,0.f};
  int jb = row_start[n], je = row_start[n+1];
  const float* Pe = P + (size_t)jb*96;
  const float* Yv = Ye + (size_t)jb*16;
  #pragma unroll 2
  for (int j = jb; j < je; j++){
    #pragma unroll
    for (int s = 0; s < 5; s++){
      if (act[s]) acc[s] = fmaf(Pe[cols[s]], Yv[ms[s]], acc[s]);
    }
    Pe += 96; Yv += 16;
  }
  #pragma unroll
  for (int s = 0; s < 5; s++){
    int idx = lane + s*64;
    if (act[s]) abuf[w][idx] = acc[s] * (1.0f/16.0f);
  }
  __syncthreads();

  // ---- mix: A @ W_mix[lmap], sc = h @ W_sc[lmap]
  float amv[5], scv[5];
  #pragma unroll
  for (int it = 0; it < 5; it++){
    int idx = it*64 + lane;
    amv[it] = 0.f; scv[it] = 0.f;
    if (idx < 288){
      int m = idx >> 5, d = idx & 31;
      int l = (m >= 4) ? 2 : ((m >= 1) ? 1 : 0);
      const float* wm = Wm + l*1024 + d;
      const float* ws = Ws + l*1024 + d;
      float a2 = 0.f, sc = 0.f;
      #pragma unroll
      for (int c = 0; c < 32; c++){
        a2 = fmaf(abuf[w][m*32+c], wm[c*32], a2);
        sc = fmaf(hbuf[w][m*32+c], ws[c*32], sc);
      }
      amv[it] = a2; scv[it] = sc;
    }
  }
  __syncthreads();
  #pragma unroll
  for (int it = 0; it < 5; it++){ int idx = it*64+lane; if (idx < 288) abuf[w][idx] = amv[it]; }
  __syncthreads();

  int d = lane & 31;
  float sval = abuf[w][d];
  int spec = species[n];
  float p1 = Wp1[spec*C+d], p2 = Wp2[spec*C+d], p3 = Wp3[spec*C+d];
  float f = p1 + p2*sval + p3*sval*sval;
  #pragma unroll
  for (int it = 0; it < 5; it++){
    int idx = it*64 + lane;
    if (idx < 288){
      float hn = amv[it]*f + scv[it];
      hg[(long)n*288+idx] = hn;
      hbuf[w][idx] = hn;
    }
  }
  __syncthreads();

  int g = batch[n];
  float dv0 = 0.f, dv1 = 0.f, dv2 = 0.f, ev = 0.f;
  if (lane < 32){
    dv0 = hbuf[w][32+lane]*wDv[lane];
    dv1 = hbuf[w][64+lane]*wDv[lane];
    dv2 = hbuf[w][96+lane]*wDv[lane];
  }
  if (iter == 0){
    if (lane < 32) ev = hbuf[w][lane]*wEv[lane];
  } else {
    if (lane < 16){
      float hid = 0.f;
      #pragma unroll
      for (int c = 0; c < 32; c++) hid = fmaf(hbuf[w][c], Whg[c*16+lane], hid);
      hid = silu_f(hid);
      ev = hid * wE2g[lane];
    }
  }
  #pragma unroll
  for (int off = 16; off >= 1; off >>= 1){
    ev  += __shfl_down(ev,  off);
    dv0 += __shfl_down(dv0, off);
    dv1 += __shfl_down(dv1, off);
    dv2 += __shfl_down(dv2, off);
  }
  if (lane == 0){
    atomicAdd(&glds[g][0], ev);
    atomicAdd(&glds[g][1], dv0);
    atomicAdd(&glds[g][2], dv1);
    atomicAdd(&glds[g][3], dv2);
  }
  __syncthreads();
  if (tid < NG*4){
    float v = glds[tid>>2][tid&3];
    if (v != 0.f) atomicAdd(out + tid, v);
  }
}

// ---------------------------------------------------------------- launch
extern "C" void kernel_launch(void* const* d_in, const int* in_sizes, int n_in,
                              void* d_out, int out_size, void* d_ws, size_t ws_size,
                              hipStream_t stream){
  const float* positions       = (const float*)d_in[0];
  const float* node_attrs      = (const float*)d_in[1];
  const float* charges         = (const float*)d_in[2];
  const float* atomic_energies = (const float*)d_in[3];
  const float* W_embed         = (const float*)d_in[4];
  const float* R0              = (const float*)d_in[5];
  const float* R1              = (const float*)d_in[6];
  const float* R2              = (const float*)d_in[7];
  const float* R3              = (const float*)d_in[8];
  const float* W_mix           = (const float*)d_in[9];
  const float* W_sc            = (const float*)d_in[10];
  const float* Wp1             = (const float*)d_in[11];
  const float* Wp2             = (const float*)d_in[12];
  const float* Wp3             = (const float*)d_in[13];
  const float* wE1             = (const float*)d_in[14];
  const float* wD1             = (const float*)d_in[15];
  const float* Wh              = (const float*)d_in[16];
  const float* wE2             = (const float*)d_in[17];
  const float* wD2             = (const float*)d_in[18];
  const int*   edge_index      = (const int*)d_in[19];
  const int*   batch           = (const int*)d_in[20];
  float* out = (float*)d_out;

  char* wsp = (char*)d_ws;
  float* P   = (float*)wsp; wsp += sizeof(float)*(size_t)N_EDGES*96;
  float* Ye  = (float*)wsp; wsp += sizeof(float)*(size_t)N_EDGES*16;
  float* RBt = (float*)wsp; wsp += sizeof(float)*(size_t)NB*N_EDGES;
  float* hg  = (float*)wsp; wsp += sizeof(float)*(size_t)N_NODES*288;
  int* counts    = (int*)wsp; wsp += sizeof(int)*N_NODES;
  int* row_start = (int*)wsp; wsp += sizeof(int)*(N_NODES+64);
  int* cursor    = (int*)wsp; wsp += sizeof(int)*N_NODES;
  int* order     = (int*)wsp; wsp += sizeof(int)*N_EDGES;
  int* snd_perm  = (int*)wsp; wsp += sizeof(int)*N_EDGES;
  int* species   = (int*)wsp; wsp += sizeof(int)*N_NODES;

  hipMemsetAsync(d_out, 0, 64*sizeof(float), stream);
  hipMemsetAsync(counts, 0, N_NODES*sizeof(int), stream);
  hipMemsetAsync(hg, 0, sizeof(float)*(size_t)N_NODES*288, stream);

  hist_kernel<<<N_EDGES/256, 256, 0, stream>>>(edge_index, counts);
  scan_kernel<<<1, 256, 0, stream>>>(counts, row_start, cursor);
  fill_kernel<<<N_EDGES/256, 256, 0, stream>>>(edge_index, cursor, order);
  spec_kernel<<<N_NODES/256, 256, 0, stream>>>(node_attrs, atomic_energies, charges,
                                               positions, batch, species, out);
  h0_kernel<<<N_NODES*32/256, 256, 0, stream>>>(species, W_embed, hg);
  geom_kernel<<<N_EDGES/128, 128, 0, stream>>>(positions, edge_index, order,
                                               snd_perm, Ye, RBt);

  for (int i = 0; i < 2; i++){
    edge_kernel<<<N_EDGES/128, 128, 0, stream>>>(R0 + i*NB*H, R1 + i*H*H, R2 + i*H*H,
                                                 R3 + i*H*96, RBt, hg, snd_perm, P);
    node_kernel<<<N_NODES/4, 256, 0, stream>>>(P, Ye, row_start, hg,
                                               W_mix + i*3*C*C, W_sc + i*3*C*C,
                                               Wp1 + i*Zn*C, Wp2 + i*Zn*C, Wp3 + i*Zn*C,
                                               species, batch,
                                               wE1, (i == 0) ? wD1 : wD2,
                                               Wh, wE2, i, out);
  }
}